// Round 1
// baseline (728.286 us; speedup 1.0000x reference)
//
#include <hip/hip_runtime.h>
#include <hip/hip_bf16.h>
#include <math.h>

// Problem constants
#define B_   64
#define T_   1024
#define AD   128   // ATTN_DIM
#define RD   1024  // RNN_DIM
#define ED   512   // ENC_DIM
#define NF   32    // N_FILT
#define KS   31    // KSIZE
#define PADW 15

// scores kernel tiling
#define TT   32    // t-tile per block
#define EC   32    // e-chunk
#define SWK  36    // W_key LDS stride (pad for b128 alignment + conflict-free)
#define SK   36    // keys LDS stride

// ---------------------------------------------------------------------------
// K1: q_proj[b][a] = dot(query[b][:RD], W_query[a][:RD])
// grid(64), block(128)
__global__ __launch_bounds__(128) void qproj_kernel(
    const float* __restrict__ query, const float* __restrict__ Wq,
    float* __restrict__ qp) {
  __shared__ float q_s[RD];
  const int b = blockIdx.x, tid = threadIdx.x;
  for (int i = tid; i < RD / 4; i += 128)
    *(float4*)&q_s[i * 4] = *(const float4*)&query[b * RD + i * 4];
  __syncthreads();
  const float* wr = &Wq[(size_t)tid * RD];
  float acc = 0.f;
  for (int e = 0; e < RD; e += 4) {
    float4 w = *(const float4*)&wr[e];
    acc += w.x * q_s[e] + w.y * q_s[e + 1] + w.z * q_s[e + 2] + w.w * q_s[e + 3];
  }
  qp[b * AD + tid] = acc;
}

// ---------------------------------------------------------------------------
// K2: fused location-conv + loc_proj + k_proj + tanh + scores
// grid(T/TT, B), block(256). Each block: one b, 32 t's, all 128 a's.
// Thread (ag,tg): a0=ag, a1=ag+64; t = t0 + tg*8 + j (j<8).
__global__ __launch_bounds__(256) void scores_kernel(
    const float* __restrict__ keys, const float* __restrict__ awc,
    const float* __restrict__ Wc, const float* __restrict__ Wlp,
    const float* __restrict__ Wk, const float* __restrict__ Wa,
    const float* __restrict__ qp, float* __restrict__ scores) {
  __shared__ float Wk_s[AD * SWK];     // 4608 f
  __shared__ float keys_s[TT * SK];    // 1152 f
  __shared__ float Wlp_s[AD * 33];     // 4224 f
  __shared__ float loc_s[TT * 33];     // 1056 f
  __shared__ float Wc_s[NF * KS];      // 992 f
  __shared__ float awc_s[TT + KS - 1]; // 62 f
  __shared__ float qp_s[AD];
  __shared__ float Wa_s[AD];

  const int tid = threadIdx.x;
  const int b = blockIdx.y;
  const int t0 = blockIdx.x * TT;
  const int ag = tid & 63;
  const int tg = tid >> 6;
  const int a0 = ag, a1 = ag + 64;

  // ---- prologue staging ----
  for (int i = tid; i < NF * KS; i += 256) Wc_s[i] = Wc[i];
  for (int i = tid; i < AD * NF; i += 256)
    Wlp_s[(i >> 5) * 33 + (i & 31)] = Wlp[i];
  if (tid < AD) { qp_s[tid] = qp[b * AD + tid]; Wa_s[tid] = Wa[tid]; }
  if (tid < TT + KS - 1) {
    int gt = t0 - PADW + tid;
    awc_s[tid] = (gt >= 0 && gt < T_) ? awc[b * T_ + gt] : 0.0f;
  }
  __syncthreads();

  // ---- conv: loc_s[t][f] = sum_k Wc[f][k] * awc[t-15+k] ----
  for (int i = tid; i < TT * NF; i += 256) {
    int t = i >> 5, f = i & 31;
    const float* wf = &Wc_s[f * KS];
    float s = 0.f;
#pragma unroll
    for (int k = 0; k < KS; ++k) s += wf[k] * awc_s[t + k];
    loc_s[t * 33 + f] = s;
  }

  // ---- main loop: k_proj accumulate over e-chunks ----
  float acc0[8], acc1[8];
#pragma unroll
  for (int j = 0; j < 8; ++j) { acc0[j] = 0.f; acc1[j] = 0.f; }

  const size_t keybase = ((size_t)b * T_ + t0) * ED;

  for (int ec = 0; ec < ED; ec += EC) {
    __syncthreads();  // protect LDS buffers from previous iteration readers
#pragma unroll
    for (int i = 0; i < 4; ++i) {
      int p = i * 256 + tid;            // 0..1023 float4 slots (128a x 8)
      int a = p >> 3, ei = p & 7;
      *(float4*)&Wk_s[a * SWK + ei * 4] =
          *(const float4*)&Wk[(size_t)a * ED + ec + ei * 4];
    }
    {
      int t = tid >> 3, ei = tid & 7;   // 256 slots = 32t x 8
      *(float4*)&keys_s[t * SK + ei * 4] =
          *(const float4*)&keys[keybase + (size_t)t * ED + ec + ei * 4];
    }
    __syncthreads();
#pragma unroll
    for (int e = 0; e < EC; e += 4) {
      float4 w0 = *(const float4*)&Wk_s[a0 * SWK + e];
      float4 w1 = *(const float4*)&Wk_s[a1 * SWK + e];
#pragma unroll
      for (int j = 0; j < 8; ++j) {
        float4 kv = *(const float4*)&keys_s[(tg * 8 + j) * SK + e];  // broadcast
        acc0[j] += w0.x * kv.x + w0.y * kv.y + w0.z * kv.z + w0.w * kv.w;
        acc1[j] += w1.x * kv.x + w1.y * kv.y + w1.z * kv.z + w1.w * kv.w;
      }
    }
  }

  // ---- epilogue: + q_proj + loc_feat, tanh, dot with W_attn, wave-reduce ----
  const float wa0 = Wa_s[a0], wa1 = Wa_s[a1];
  const float q0 = qp_s[a0], q1 = qp_s[a1];
#pragma unroll
  for (int j = 0; j < 8; ++j) {
    int t = tg * 8 + j;
    float lf0 = 0.f, lf1 = 0.f;
#pragma unroll
    for (int f = 0; f < NF; ++f) {
      float l = loc_s[t * 33 + f];
      lf0 += Wlp_s[a0 * 33 + f] * l;
      lf1 += Wlp_s[a1 * 33 + f] * l;
    }
    float p = wa0 * tanhf(acc0[j] + q0 + lf0) + wa1 * tanhf(acc1[j] + q1 + lf1);
#pragma unroll
    for (int off = 32; off >= 1; off >>= 1) p += __shfl_xor(p, off, 64);
    if (ag == 0) scores[b * T_ + t0 + t] = p;
  }
}

// ---------------------------------------------------------------------------
// K3: softmax over T per batch row (mask applied; mask is all-False here)
// grid(64), block(256): each thread owns 4 consecutive t's.
__global__ __launch_bounds__(256) void softmax_kernel(
    const float* __restrict__ scores, const unsigned char* __restrict__ mask,
    float* __restrict__ attn) {
  const int b = blockIdx.x, tid = threadIdx.x;
  __shared__ float redm[4], reds[4];

  float4 s4 = *(const float4*)&scores[b * T_ + tid * 4];
  uchar4 m4 = *(const uchar4*)&mask[b * T_ + tid * 4];
  if (m4.x) s4.x = -INFINITY;
  if (m4.y) s4.y = -INFINITY;
  if (m4.z) s4.z = -INFINITY;
  if (m4.w) s4.w = -INFINITY;

  float mx = fmaxf(fmaxf(s4.x, s4.y), fmaxf(s4.z, s4.w));
#pragma unroll
  for (int off = 32; off >= 1; off >>= 1) mx = fmaxf(mx, __shfl_xor(mx, off, 64));
  if ((tid & 63) == 0) redm[tid >> 6] = mx;
  __syncthreads();
  mx = fmaxf(fmaxf(redm[0], redm[1]), fmaxf(redm[2], redm[3]));

  float e0 = expf(s4.x - mx), e1 = expf(s4.y - mx);
  float e2 = expf(s4.z - mx), e3 = expf(s4.w - mx);
  float sum = e0 + e1 + e2 + e3;
#pragma unroll
  for (int off = 32; off >= 1; off >>= 1) sum += __shfl_xor(sum, off, 64);
  if ((tid & 63) == 0) reds[tid >> 6] = sum;
  __syncthreads();
  sum = reds[0] + reds[1] + reds[2] + reds[3];

  float inv = 1.0f / sum;
  float4 o4 = {e0 * inv, e1 * inv, e2 * inv, e3 * inv};
  *(float4*)&attn[b * T_ + tid * 4] = o4;
}

// ---------------------------------------------------------------------------
// K4: wv_part[b][tc][e] = sum_{t in chunk tc} attn[b][t] * values[b][t][e]
// grid(16, 64), block(128): each thread a float4 of e; 64 t's per block.
__global__ __launch_bounds__(128) void wvsum_kernel(
    const float* __restrict__ values, const float* __restrict__ attn,
    float* __restrict__ wvp) {
  const int tc = blockIdx.x, b = blockIdx.y, tid = threadIdx.x;
  __shared__ float at_s[64];
  if (tid < 64) at_s[tid] = attn[b * T_ + tc * 64 + tid];
  __syncthreads();
  float4 acc = {0.f, 0.f, 0.f, 0.f};
  const float* vbase = values + ((size_t)b * T_ + tc * 64) * ED + tid * 4;
#pragma unroll 4
  for (int t = 0; t < 64; ++t) {
    float a = at_s[t];
    float4 v = *(const float4*)&vbase[(size_t)t * ED];
    acc.x = fmaf(a, v.x, acc.x);
    acc.y = fmaf(a, v.y, acc.y);
    acc.z = fmaf(a, v.z, acc.z);
    acc.w = fmaf(a, v.w, acc.w);
  }
  *(float4*)&wvp[((b * 16 + tc) * ED) + tid * 4] = acc;
}

// ---------------------------------------------------------------------------
// K5: context[b][f] = sum_e W_value[f][e] * (sum_tc wv_part[b][tc][e])
// grid(64), block(256)
__global__ __launch_bounds__(256) void context_kernel(
    const float* __restrict__ wvp, const float* __restrict__ Wv,
    float* __restrict__ ctx) {
  const int b = blockIdx.x, tid = threadIdx.x;
  __shared__ float wv_s[ED];
  for (int e = tid; e < ED; e += 256) {
    float s = 0.f;
#pragma unroll
    for (int p = 0; p < 16; ++p) s += wvp[((b * 16 + p) * ED) + e];
    wv_s[e] = s;
  }
  __syncthreads();
  for (int f = tid; f < ED; f += 256) {
    const float* wr = &Wv[(size_t)f * ED];
    float acc = 0.f;
    for (int e = 0; e < ED; e += 4) {
      float4 w = *(const float4*)&wr[e];
      acc += w.x * wv_s[e] + w.y * wv_s[e + 1] + w.z * wv_s[e + 2] + w.w * wv_s[e + 3];
    }
    ctx[b * ED + f] = acc;
  }
}

// ---------------------------------------------------------------------------
extern "C" void kernel_launch(void* const* d_in, const int* in_sizes, int n_in,
                              void* d_out, int out_size, void* d_ws, size_t ws_size,
                              hipStream_t stream) {
  const float* query = (const float*)d_in[0];   // (64,1024)
  const float* keys  = (const float*)d_in[1];   // (64,1024,512)
  const float* values= (const float*)d_in[2];   // (64,1024,512)
  const float* awc   = (const float*)d_in[3];   // (64,1024)
  const unsigned char* mask = (const unsigned char*)d_in[4]; // (64,1024) bool
  const float* Wc    = (const float*)d_in[5];   // (32,1,31)
  const float* Wlp   = (const float*)d_in[6];   // (128,32)
  const float* Wq    = (const float*)d_in[7];   // (128,1024)
  const float* Wk    = (const float*)d_in[8];   // (128,512)
  const float* Wv    = (const float*)d_in[9];   // (512,512)
  const float* Wa    = (const float*)d_in[10];  // (1,128)

  float* ctx  = (float*)d_out;                  // (64,512)
  float* attn = (float*)d_out + B_ * ED;        // (64,1024)

  float* ws = (float*)d_ws;
  float* qp     = ws;                           // 64*128
  float* scores = ws + B_ * AD;                 // 64*1024
  float* wvp    = ws + B_ * AD + B_ * T_;       // 64*16*512

  qproj_kernel<<<B_, 128, 0, stream>>>(query, Wq, qp);
  scores_kernel<<<dim3(T_ / TT, B_), 256, 0, stream>>>(keys, awc, Wc, Wlp, Wk, Wa, qp, scores);
  softmax_kernel<<<B_, 256, 0, stream>>>(scores, mask, attn);
  wvsum_kernel<<<dim3(16, B_), 128, 0, stream>>>(values, attn, wvp);
  context_kernel<<<B_, 256, 0, stream>>>(wvp, Wv, ctx);
}

// Round 2
// 360.104 us; speedup vs baseline: 2.0224x; 2.0224x over previous
//
#include <hip/hip_runtime.h>
#include <math.h>

#define B_   64
#define T_   1024
#define AD   128
#define RD   1024
#define ED   512
#define NF   32
#define KS   31
#define PADW 15

#define SA   72   // As/Bs LDS row stride (shorts): 64 + 8 pad, rows 16B-aligned
#define SL   40   // loc LDS row stride (shorts)

typedef short bf16x8 __attribute__((ext_vector_type(8)));
typedef float f32x4  __attribute__((ext_vector_type(4)));

__device__ __forceinline__ short f2bf(float x) {
  union { float f; unsigned u; } v; v.f = x;
  unsigned r = (v.u + 0x7FFFu + ((v.u >> 16) & 1u)) >> 16;  // RNE
  return (short)r;
}

__device__ __forceinline__ float tanh_fast(float x) {
  float t = __expf(2.0f * x);
  return (t - 1.0f) * __builtin_amdgcn_rcpf(t + 1.0f);
}

// ---------------------------------------------------------------------------
// P1: convert W_key (128x512) and W_loc_proj (128x32) to bf16. 68*256 float4s.
__global__ __launch_bounds__(256) void prepw_kernel(
    const float* __restrict__ Wk, const float* __restrict__ Wlp,
    short* __restrict__ Wk16, short* __restrict__ Wlp16) {
  int p = blockIdx.x * 256 + threadIdx.x;
  const float* src; short* dst; int off;
  if (p < 16384) { src = Wk; dst = Wk16; off = p; }
  else           { src = Wlp; dst = Wlp16; off = p - 16384; }
  float4 v = *(const float4*)&src[off * 4];
  short4 h = { f2bf(v.x), f2bf(v.y), f2bf(v.z), f2bf(v.w) };
  *(short4*)&dst[off * 4] = h;
}

// ---------------------------------------------------------------------------
// P2: location conv: loc_g[b][t][f] = sum_k Wc[f][k]*awc[b][t-15+k], bf16 out.
__global__ __launch_bounds__(256) void conv_kernel(
    const float* __restrict__ awc, const float* __restrict__ Wc,
    short* __restrict__ loc_g) {
  __shared__ float awc_s[128 + KS - 1];
  __shared__ float wc_s[NF * KS];
  const int b = blockIdx.y, t0 = blockIdx.x * 128, tid = threadIdx.x;
  for (int i = tid; i < NF * KS; i += 256) wc_s[i] = Wc[i];
  if (tid < 128 + KS - 1) {
    int gt = t0 - PADW + tid;
    awc_s[tid] = (gt >= 0 && gt < T_) ? awc[b * T_ + gt] : 0.0f;
  }
  __syncthreads();
  const int t = tid & 127, fh = (tid >> 7) * 16;
  for (int fq = 0; fq < 4; ++fq) {
    float s0 = 0.f, s1 = 0.f, s2 = 0.f, s3 = 0.f;
    const float* w0 = &wc_s[(fh + fq * 4 + 0) * KS];
    const float* w1 = &wc_s[(fh + fq * 4 + 1) * KS];
    const float* w2 = &wc_s[(fh + fq * 4 + 2) * KS];
    const float* w3 = &wc_s[(fh + fq * 4 + 3) * KS];
#pragma unroll
    for (int k = 0; k < KS; ++k) {
      float aw = awc_s[t + k];
      s0 += w0[k] * aw; s1 += w1[k] * aw; s2 += w2[k] * aw; s3 += w3[k] * aw;
    }
    short4 h = { f2bf(s0), f2bf(s1), f2bf(s2), f2bf(s3) };
    *(short4*)&loc_g[((size_t)(b * T_ + t0 + t)) * NF + fh + fq * 4] = h;
  }
}

// ---------------------------------------------------------------------------
// P3: q_proj[b][a] = dot(query[b], W_query[a]); 2-way k-split per block.
__global__ __launch_bounds__(256) void qproj_kernel(
    const float* __restrict__ query, const float* __restrict__ Wq,
    float* __restrict__ qp) {
  __shared__ float q_s[RD];
  __shared__ float red[AD];
  const int b = blockIdx.x, tid = threadIdx.x;
  *(float4*)&q_s[tid * 4] = *(const float4*)&query[b * RD + tid * 4];
  __syncthreads();
  const int a = tid & 127, kh = tid >> 7;
  const float* wr = &Wq[(size_t)a * RD + kh * 512];
  const float* qr = &q_s[kh * 512];
  float acc = 0.f;
  for (int e = 0; e < 512; e += 4) {
    float4 w = *(const float4*)&wr[e];
    acc += w.x * qr[e] + w.y * qr[e + 1] + w.z * qr[e + 2] + w.w * qr[e + 3];
  }
  if (kh == 1) red[a] = acc;
  __syncthreads();
  if (kh == 0) qp[b * AD + a] = acc + red[a];
}

// ---------------------------------------------------------------------------
// K-GEMM scores: C[t][a] = sum_e keys*Wk + sum_f loc*Wlp; +qp, tanh, Wa-dot.
// grid(8,64), 256 threads (4 waves, 2x2 of 64x64 tiles), BK=64, K=512+32.
__global__ __launch_bounds__(256, 3) void scores_kernel(
    const float* __restrict__ keys, const short* __restrict__ Wk16,
    const short* __restrict__ Wlp16, const short* __restrict__ loc_g,
    const float* __restrict__ qp, const float* __restrict__ Wa,
    float* __restrict__ scores) {
  __shared__ alignas(16) short As[128 * SA];   // keys tile bf16
  __shared__ alignas(16) short Bs[128 * SA];   // Wk / Wlp tile bf16
  __shared__ alignas(16) short Ls[128 * SL];   // loc tile bf16
  __shared__ float qp_s[AD], wa_s[AD];
  __shared__ float sc_s[128 * 2];

  const int tid = threadIdx.x;
  const int b = blockIdx.y, t0 = blockIdx.x * 128;
  const int lane = tid & 63, wave = tid >> 6;
  const int wm = wave >> 1, wn = wave & 1;
  const int m16 = lane & 15, s4 = lane >> 4;

  if (tid < AD) { qp_s[tid] = qp[b * AD + tid]; wa_s[tid] = Wa[tid]; }
  // stage loc tile: 128 rows x 32 bf16
#pragma unroll
  for (int i = 0; i < 4; ++i) {
    int p = i * 256 + tid, r = p >> 3, c = (p & 7) * 4;
    *(short4*)&Ls[r * SL + c] =
        *(const short4*)&loc_g[((size_t)(b * T_ + t0 + r)) * NF + c];
  }

  f32x4 acc[4][4];
#pragma unroll
  for (int mt = 0; mt < 4; ++mt)
#pragma unroll
    for (int nt = 0; nt < 4; ++nt) acc[mt][nt] = (f32x4){0.f, 0.f, 0.f, 0.f};

  const int arow = wm * 64 + m16, brow = wn * 64 + m16;
  const float* kb = keys + ((size_t)(b * T_ + t0)) * ED;

  for (int kc = 0; kc < 8; ++kc) {
    __syncthreads();
    // stage A: keys 128x64 fp32 -> bf16
#pragma unroll
    for (int i = 0; i < 8; ++i) {
      int p = i * 256 + tid, e4 = p & 15, r = p >> 4;
      float4 v = *(const float4*)&kb[(size_t)r * ED + kc * 64 + e4 * 4];
      short4 h = { f2bf(v.x), f2bf(v.y), f2bf(v.z), f2bf(v.w) };
      *(short4*)&As[r * SA + e4 * 4] = h;
    }
    // stage B: Wk16 128x64 copy
#pragma unroll
    for (int i = 0; i < 4; ++i) {
      int p = i * 256 + tid, c8 = p & 7, r = p >> 3;
      *(int4*)&Bs[r * SA + c8 * 8] =
          *(const int4*)&Wk16[(size_t)r * ED + kc * 64 + c8 * 8];
    }
    __syncthreads();
#pragma unroll
    for (int kk = 0; kk < 64; kk += 32) {
      bf16x8 af[4], bfr[4];
      const int ko = kk + s4 * 8;
#pragma unroll
      for (int mt = 0; mt < 4; ++mt)
        af[mt] = *(const bf16x8*)&As[(arow + mt * 16) * SA + ko];
#pragma unroll
      for (int nt = 0; nt < 4; ++nt)
        bfr[nt] = *(const bf16x8*)&Bs[(brow + nt * 16) * SA + ko];
#pragma unroll
      for (int mt = 0; mt < 4; ++mt)
#pragma unroll
        for (int nt = 0; nt < 4; ++nt)
          acc[mt][nt] = __builtin_amdgcn_mfma_f32_16x16x32_bf16(
              af[mt], bfr[nt], acc[mt][nt], 0, 0, 0);
    }
  }

  // loc chunk (K=32): A from Ls, B = Wlp16
  __syncthreads();
#pragma unroll
  for (int i = 0; i < 2; ++i) {
    int p = i * 256 + tid, c = p & 3, r = p >> 2;
    *(int4*)&Bs[r * SA + c * 8] = *(const int4*)&Wlp16[r * NF + c * 8];
  }
  __syncthreads();
  {
    bf16x8 af[4], bfr[4];
#pragma unroll
    for (int mt = 0; mt < 4; ++mt) {
      union { bf16x8 v; short4 h[2]; } u;
      u.h[0] = *(const short4*)&Ls[(arow + mt * 16) * SL + s4 * 8];
      u.h[1] = *(const short4*)&Ls[(arow + mt * 16) * SL + s4 * 8 + 4];
      af[mt] = u.v;
    }
#pragma unroll
    for (int nt = 0; nt < 4; ++nt)
      bfr[nt] = *(const bf16x8*)&Bs[(brow + nt * 16) * SA + s4 * 8];
#pragma unroll
    for (int mt = 0; mt < 4; ++mt)
#pragma unroll
      for (int nt = 0; nt < 4; ++nt)
        acc[mt][nt] = __builtin_amdgcn_mfma_f32_16x16x32_bf16(
            af[mt], bfr[nt], acc[mt][nt], 0, 0, 0);
  }

  // epilogue: + qp, tanh, Wa-dot, reduce over a
  float qv[4], wv[4];
#pragma unroll
  for (int nt = 0; nt < 4; ++nt) {
    int a = wn * 64 + nt * 16 + m16;
    qv[nt] = qp_s[a]; wv[nt] = wa_s[a];
  }
#pragma unroll
  for (int mt = 0; mt < 4; ++mt) {
#pragma unroll
    for (int r = 0; r < 4; ++r) {
      float p = 0.f;
#pragma unroll
      for (int nt = 0; nt < 4; ++nt)
        p += wv[nt] * tanh_fast(acc[mt][nt][r] + qv[nt]);
      p += __shfl_xor(p, 1); p += __shfl_xor(p, 2);
      p += __shfl_xor(p, 4); p += __shfl_xor(p, 8);
      if (m16 == 0) sc_s[(wm * 64 + mt * 16 + s4 * 4 + r) * 2 + wn] = p;
    }
  }
  __syncthreads();
  if (tid < 128)
    scores[(size_t)b * T_ + t0 + tid] = sc_s[tid * 2] + sc_s[tid * 2 + 1];
}

// ---------------------------------------------------------------------------
__global__ __launch_bounds__(256) void softmax_kernel(
    const float* __restrict__ scores, const unsigned char* __restrict__ mask,
    float* __restrict__ attn) {
  const int b = blockIdx.x, tid = threadIdx.x;
  __shared__ float redm[4], reds[4];

  float4 s4 = *(const float4*)&scores[b * T_ + tid * 4];
  uchar4 m4 = *(const uchar4*)&mask[b * T_ + tid * 4];
  if (m4.x) s4.x = -INFINITY;
  if (m4.y) s4.y = -INFINITY;
  if (m4.z) s4.z = -INFINITY;
  if (m4.w) s4.w = -INFINITY;

  float mx = fmaxf(fmaxf(s4.x, s4.y), fmaxf(s4.z, s4.w));
#pragma unroll
  for (int off = 32; off >= 1; off >>= 1) mx = fmaxf(mx, __shfl_xor(mx, off, 64));
  if ((tid & 63) == 0) redm[tid >> 6] = mx;
  __syncthreads();
  mx = fmaxf(fmaxf(redm[0], redm[1]), fmaxf(redm[2], redm[3]));

  float e0 = expf(s4.x - mx), e1 = expf(s4.y - mx);
  float e2 = expf(s4.z - mx), e3 = expf(s4.w - mx);
  float sum = e0 + e1 + e2 + e3;
#pragma unroll
  for (int off = 32; off >= 1; off >>= 1) sum += __shfl_xor(sum, off, 64);
  if ((tid & 63) == 0) reds[tid >> 6] = sum;
  __syncthreads();
  sum = reds[0] + reds[1] + reds[2] + reds[3];

  float inv = 1.0f / sum;
  float4 o4 = { e0 * inv, e1 * inv, e2 * inv, e3 * inv };
  *(float4*)&attn[b * T_ + tid * 4] = o4;
}

// ---------------------------------------------------------------------------
// K4: wvp[b][p][e] = sum_{t in 16-chunk p} attn*values; fully coalesced.
__global__ __launch_bounds__(256) void wvsum_kernel(
    const float* __restrict__ values, const float* __restrict__ attn,
    float* __restrict__ wvp) {
  const int tc = blockIdx.x, b = blockIdx.y, tid = threadIdx.x;
  __shared__ float at_s[32];
  if (tid < 32) at_s[tid] = attn[b * T_ + tc * 32 + tid];
  __syncthreads();
  const int e4 = tid & 127, th = tid >> 7;
  const float* vb = values + ((size_t)(b * T_ + tc * 32 + th * 16)) * ED + e4 * 4;
  float4 acc = {0.f, 0.f, 0.f, 0.f};
#pragma unroll
  for (int t = 0; t < 16; ++t) {
    float a = at_s[th * 16 + t];
    float4 v = *(const float4*)&vb[(size_t)t * ED];
    acc.x = fmaf(a, v.x, acc.x); acc.y = fmaf(a, v.y, acc.y);
    acc.z = fmaf(a, v.z, acc.z); acc.w = fmaf(a, v.w, acc.w);
  }
  *(float4*)&wvp[((size_t)(b * 64 + tc * 2 + th)) * ED + e4 * 4] = acc;
}

// ---------------------------------------------------------------------------
// K5: ctx[b][f] = sum_e Wv[f][e] * (sum_p wvp[b][p][e]); f-split by 128.
__global__ __launch_bounds__(256) void context_kernel(
    const float* __restrict__ wvp, const float* __restrict__ Wv,
    float* __restrict__ ctx) {
  const int fq = blockIdx.x, b = blockIdx.y, tid = threadIdx.x;
  __shared__ float wv_s[ED];
  __shared__ float red[128];
  for (int e = tid; e < ED; e += 256) {
    float s = 0.f;
    const float* base = &wvp[(size_t)b * 64 * ED + e];
#pragma unroll
    for (int p = 0; p < 64; ++p) s += base[p * ED];
    wv_s[e] = s;
  }
  __syncthreads();
  const int fl = tid & 127, eh = tid >> 7;
  const int f = fq * 128 + fl;
  const float* wr = &Wv[(size_t)f * ED + eh * 256];
  const float* qr = &wv_s[eh * 256];
  float acc = 0.f;
  for (int e = 0; e < 256; e += 4) {
    float4 w = *(const float4*)&wr[e];
    acc += w.x * qr[e] + w.y * qr[e + 1] + w.z * qr[e + 2] + w.w * qr[e + 3];
  }
  if (eh == 1) red[fl] = acc;
  __syncthreads();
  if (eh == 0) ctx[b * ED + f] = acc + red[fl];
}

// ---------------------------------------------------------------------------
extern "C" void kernel_launch(void* const* d_in, const int* in_sizes, int n_in,
                              void* d_out, int out_size, void* d_ws, size_t ws_size,
                              hipStream_t stream) {
  const float* query = (const float*)d_in[0];
  const float* keys  = (const float*)d_in[1];
  const float* values= (const float*)d_in[2];
  const float* awc   = (const float*)d_in[3];
  const unsigned char* mask = (const unsigned char*)d_in[4];
  const float* Wc    = (const float*)d_in[5];
  const float* Wlp   = (const float*)d_in[6];
  const float* Wq    = (const float*)d_in[7];
  const float* Wk    = (const float*)d_in[8];
  const float* Wv    = (const float*)d_in[9];
  const float* Wa    = (const float*)d_in[10];

  float* ctx  = (float*)d_out;              // (64,512)
  float* attn = (float*)d_out + B_ * ED;    // (64,1024)

  float* ws = (float*)d_ws;
  float* qp      = ws;                            // 8192 f
  float* scoresB = qp + B_ * AD;                  // 65536 f
  float* wvp     = scoresB + B_ * T_;             // 64*64*512 f = 2M f
  short* Wk16    = (short*)(wvp + (size_t)B_ * 64 * ED);  // 65536 sh
  short* Wlp16   = Wk16 + AD * ED;                // 4096 sh
  short* loc_g   = Wlp16 + AD * NF;               // 64*1024*32 sh

  prepw_kernel<<<68, 256, 0, stream>>>(Wk, Wlp, Wk16, Wlp16);
  conv_kernel<<<dim3(8, 64), 256, 0, stream>>>(awc, Wc, loc_g);
  qproj_kernel<<<B_, 256, 0, stream>>>(query, Wq, qp);
  scores_kernel<<<dim3(8, 64), 256, 0, stream>>>(keys, Wk16, Wlp16, loc_g, qp, Wa, scoresB);
  softmax_kernel<<<B_, 256, 0, stream>>>(scoresB, mask, attn);
  wvsum_kernel<<<dim3(32, B_), 256, 0, stream>>>(values, attn, wvp);
  context_kernel<<<dim3(4, B_), 256, 0, stream>>>(wvp, Wv, ctx);
}